// Round 7
// baseline (2220.405 us; speedup 1.0000x reference)
//
#include <hip/hip_runtime.h>
#include <cstdint>
#include <cstddef>

typedef unsigned short ushort_t;
typedef unsigned int uint_t;
typedef unsigned long long u64_t;
typedef __attribute__((ext_vector_type(8))) short frag16;
typedef __attribute__((ext_vector_type(8))) unsigned short u16x8;
typedef __attribute__((ext_vector_type(4))) float f32x4;

#define SEQ   512
#define INF   512
#define HID   1024
#define OUTF  512
#define GROUPS 16
#define BPG    16   // blocks per group
#define NB     4    // batches per group (= waves per block)
#define RPB    64   // W_hh rows (output cols) per block
#define SPIN_LIMIT (1 << 18)

__device__ __forceinline__ float b2f(ushort_t u) {
    union { unsigned int i; float f; } v; v.i = ((unsigned int)u) << 16; return v.f;
}
__device__ __forceinline__ ushort_t f2b(float f) {  // RNE fp32->bf16
    unsigned int u = __float_as_uint(f);
    unsigned int r = (u + 0x7fffu + ((u >> 16) & 1u)) >> 16;
    return (ushort_t)r;
}
__device__ __forceinline__ float fast_tanh(float s) {
    const float e = __expf(2.0f * s);
    return 1.0f - 2.0f * __builtin_amdgcn_rcpf(e + 1.0f);
}

__device__ __forceinline__ void cvt8_hilo(const float* __restrict__ src, u16x8* hi, u16x8* lo) {
    const float4 x0 = *(const float4*)src;
    const float4 x1 = *(const float4*)(src + 4);
    float xs[8] = {x0.x,x0.y,x0.z,x0.w,x1.x,x1.y,x1.z,x1.w};
    u16x8 h, l;
#pragma unroll
    for (int j = 0; j < 8; ++j) {
        const ushort_t hb = f2b(xs[j]);
        h[j] = hb;
        l[j] = f2b(xs[j] - b2f(hb));
    }
    *hi = h; if (lo) *lo = l;
}
__device__ __forceinline__ u16x8 cvt8_hi(const float* __restrict__ src) {
    const float4 x0 = *(const float4*)src;
    const float4 x1 = *(const float4*)(src + 4);
    float xs[8] = {x0.x,x0.y,x0.z,x0.w,x1.x,x1.y,x1.z,x1.w};
    u16x8 h;
#pragma unroll
    for (int j = 0; j < 8; ++j) h[j] = f2b(xs[j]);
    return h;
}

// ---------------- Phase 1: XP[m][n] = sum_k X[m,k]*Wih[n,k] + bih[n] + bhh[n] ----
__global__ __launch_bounds__(256, 2)
void xproj_kernel(const float* __restrict__ X, const float* __restrict__ Wih,
                  const float* __restrict__ bih, const float* __restrict__ bhh,
                  float* __restrict__ XP)
{
    __shared__ ushort_t Ah[128][40];
    __shared__ ushort_t Al[128][40];
    __shared__ ushort_t Bs[128][40];
    const int tid = (int)threadIdx.x;
    const int m0 = (int)blockIdx.x * 128;
    const int n0 = (int)blockIdx.y * 128;
    const int w  = tid >> 6, l = tid & 63;
    const int wm = (w & 1) * 64, wn = (w >> 1) * 64;
    const int lm = l & 15, lg = l >> 4, hk = lg * 8;
    const int sr = tid >> 2, sc = (tid & 3) * 8;

    f32x4 acc[4][4];
#pragma unroll
    for (int a = 0; a < 4; ++a)
#pragma unroll
        for (int b = 0; b < 4; ++b) { acc[a][b][0]=0.f; acc[a][b][1]=0.f; acc[a][b][2]=0.f; acc[a][b][3]=0.f; }

    for (int ko = 0; ko < INF; ko += 32) {
        __syncthreads();
        u16x8 h, lo;
        cvt8_hilo(&X[(size_t)(m0+sr)*INF + ko + sc], &h, &lo);
        *(u16x8*)&Ah[sr][sc] = h;  *(u16x8*)&Al[sr][sc] = lo;
        cvt8_hilo(&X[(size_t)(m0+sr+64)*INF + ko + sc], &h, &lo);
        *(u16x8*)&Ah[sr+64][sc] = h;  *(u16x8*)&Al[sr+64][sc] = lo;
        *(u16x8*)&Bs[sr][sc]    = cvt8_hi(&Wih[(size_t)(n0+sr)*INF + ko + sc]);
        *(u16x8*)&Bs[sr+64][sc] = cvt8_hi(&Wih[(size_t)(n0+sr+64)*INF + ko + sc]);
        __syncthreads();
        frag16 afh[4], afl[4], bf[4];
#pragma unroll
        for (int i = 0; i < 4; ++i) afh[i] = *(const frag16*)&Ah[wm + i*16 + lm][hk];
#pragma unroll
        for (int i = 0; i < 4; ++i) afl[i] = *(const frag16*)&Al[wm + i*16 + lm][hk];
#pragma unroll
        for (int i = 0; i < 4; ++i) bf[i]  = *(const frag16*)&Bs[wn + i*16 + lm][hk];
#pragma unroll
        for (int a = 0; a < 4; ++a)
#pragma unroll
            for (int b = 0; b < 4; ++b) {
                acc[a][b] = __builtin_amdgcn_mfma_f32_16x16x32_bf16(afh[a], bf[b], acc[a][b], 0, 0, 0);
                acc[a][b] = __builtin_amdgcn_mfma_f32_16x16x32_bf16(afl[a], bf[b], acc[a][b], 0, 0, 0);
            }
    }

#pragma unroll
    for (int b = 0; b < 4; ++b) {
        const int n = n0 + wn + b*16 + lm;
        const float bias = bih[n] + bhh[n];
#pragma unroll
        for (int a = 0; a < 4; ++a)
#pragma unroll
            for (int q = 0; q < 4; ++q) {
                const int m = m0 + wm + a*16 + lg*4 + q;
                XP[(size_t)m * HID + n] = acc[a][b][q] + bias;
            }
    }
}

// ---------------- Phase 2: persistent scan, tagged-data exchange v2 ------------
// 256 blocks = 16 groups x 16 blocks; group g owns batches [4g,4g+4); block r
// owns cols [64r,64r+64) (bf16 W in LDS). Wire format (proven round 6): one
// 8-byte agent-scope relaxed atomic word = (packed_bf16 hi|lo<<16) << 32 | (t+1).
// v2 restructure: wave w computes its own 16-col tile over FULL K (no cross-wave
// reduction, no Cred, ONE __syncthreads per step); staging pre-splits hi/lo into
// separate ushort LDS arrays so the MFMA loop has zero unpack VALU; 4 interleaved
// accumulators keep MFMA ILP=4. Cross-step LDS reuse safe: a wave enters staging
// of step t+1 only after seeing all group tags t+1, which implies every wave of
// its own block stored step t, which happens after their last Hst read.
__global__ __launch_bounds__(256, 1)
void rnn_scan_kernel(const float* __restrict__ XP, const float* __restrict__ Whh,
                     u64_t* __restrict__ Hbuf)
{
    __shared__ ushort_t Ws[RPB][1032];        // 132,096 B
    __shared__ ushort_t Hhi[NB][1040];        //   8,320 B
    __shared__ ushort_t Hlo[NB][1040];        //   8,320 B  -> 148.7 KB, 1 block/CU

    const int tid = (int)threadIdx.x;
    const int w = tid >> 6, l = tid & 63;     // wave (=batch row), lane
    const int lm = l & 15, lg = l >> 4;
    const int gid = (int)blockIdx.x >> 4;
    const int r   = (int)blockIdx.x & 15;
    const int b0 = gid * NB;
    const int j0 = r * RPB;

    // Load this block's 64 W_hh rows into LDS as bf16 (once).
    {
        const int rr = tid >> 2, cq = (tid & 3) * 256;
        const float* src = Whh + (size_t)(j0 + rr) * HID + cq;
#pragma unroll
        for (int i = 0; i < 32; ++i)
            *(u16x8*)&Ws[rr][cq + i*8] = cvt8_hi(&src[i*8]);
    }
    __syncthreads();

    for (int t = 0; t < SEQ; ++t) {
        // xp prefetch (lanes 0..15 of each wave; independent of gather)
        float xpv[4];
        if (l < 16) {
#pragma unroll
            for (int q = 0; q < 4; ++q)
                xpv[q] = XP[(size_t)((b0 + q) * SEQ + t) * HID + (j0 + w*16 + l)];
        }

        float sq[4] = {0.f, 0.f, 0.f, 0.f};

        if (t > 0) {
            // ---- tagged gather: wave w pulls row (b0+w), cols l + 64j ----
            {
                const u64_t* rowp = Hbuf + ((size_t)((t - 1) & 1) * 64 + b0 + w) * 1024 + l;
                const uint_t want = (uint_t)t;     // tag written at step t-1
                u64_t v[16];
#pragma unroll
                for (int j = 0; j < 16; ++j)
                    v[j] = __hip_atomic_load(&rowp[j*64], __ATOMIC_RELAXED,
                                             __HIP_MEMORY_SCOPE_AGENT);
                int spin = 0;
                for (;;) {
                    int bad = 0;
#pragma unroll
                    for (int j = 0; j < 16; ++j) bad |= ((uint_t)v[j] != want);
                    if (!__any(bad)) break;
                    if (++spin > SPIN_LIMIT) break;   // hang-proof: finite-wrong
                    __builtin_amdgcn_s_sleep(1);
#pragma unroll
                    for (int j = 0; j < 16; ++j)
                        if ((uint_t)v[j] != want)
                            v[j] = __hip_atomic_load(&rowp[j*64], __ATOMIC_RELAXED,
                                                     __HIP_MEMORY_SCOPE_AGENT);
                }
                // stage pre-split: b16 writes (hi-write free, lo one shift)
#pragma unroll
                for (int j = 0; j < 16; ++j) {
                    const uint_t d = (uint_t)(v[j] >> 32);
                    Hhi[w][l + 64*j] = (ushort_t)d;          // low 16 bits
                    Hlo[w][l + 64*j] = (ushort_t)(d >> 16);
                }
            }
            __syncthreads();                       // the ONLY barrier per step

            // ---- MFMA: wave w, full K=1024, its 16-col tile, ILP-4 accs ----
            f32x4 acc[4];
#pragma unroll
            for (int i = 0; i < 4; ++i) { acc[i][0]=0.f; acc[i][1]=0.f; acc[i][2]=0.f; acc[i][3]=0.f; }
#pragma unroll
            for (int kk = 0; kk < 32; ++kk) {
                const int k0 = kk * 32;
                frag16 ahi, alo;
#pragma unroll
                for (int j = 0; j < 8; ++j) { ahi[j] = 0; alo[j] = 0; }
                if (lm < NB) {
                    ahi = *(const frag16*)&Hhi[lm][k0 + lg*8];
                    alo = *(const frag16*)&Hlo[lm][k0 + lg*8];
                }
                const frag16 wf = *(const frag16*)&Ws[w*16 + lm][k0 + lg*8];
                acc[kk & 3] = __builtin_amdgcn_mfma_f32_16x16x32_bf16(ahi, wf, acc[kk & 3], 0, 0, 0);
                acc[kk & 3] = __builtin_amdgcn_mfma_f32_16x16x32_bf16(alo, wf, acc[kk & 3], 0, 0, 0);
            }
#pragma unroll
            for (int q = 0; q < 4; ++q)
                sq[q] = (acc[0][q] + acc[1][q]) + (acc[2][q] + acc[3][q]);
        }

        // ---- finish: lanes 0..15 (lg==0) hold C rows 0..3 = the 4 batches ----
        if (l < 16) {
            const int jt = j0 + w*16 + l;
            u64_t* outp = Hbuf + ((size_t)(t & 1) * 64 + b0) * 1024 + jt;
#pragma unroll
            for (int q = 0; q < 4; ++q) {
                const float v = fast_tanh(sq[q] + xpv[q]);
                const ushort_t hi = f2b(v);
                const ushort_t lo = f2b(v - b2f(hi));
                const u64_t pk = ((u64_t)((uint_t)hi | ((uint_t)lo << 16)) << 32)
                               | (u64_t)(uint_t)(t + 1);   // tag t+1, never 0/poison
                __hip_atomic_store(&outp[(size_t)q * 1024], pk,
                                   __ATOMIC_RELAXED, __HIP_MEMORY_SCOPE_AGENT);
            }
        }
    }
}

// ---------------- Phase 3: Out[b][n] = sum_k H[b,k]*Who[n,k] + bho[n] ----------
__global__ __launch_bounds__(256)
void outproj_kernel(const u64_t* __restrict__ Hp, const float* __restrict__ Who,
                    const float* __restrict__ bho, float* __restrict__ Out)
{
    const int tid = (int)threadIdx.x;
    const int w = tid >> 6, l = tid & 63;
    const int lm = l & 15, lg = l >> 4, hk = lg * 8;
    const int n0 = (int)blockIdx.x * 64;

    f32x4 acc[4];
#pragma unroll
    for (int i = 0; i < 4; ++i) { acc[i][0]=0.f; acc[i][1]=0.f; acc[i][2]=0.f; acc[i][3]=0.f; }

    for (int k0 = 0; k0 < HID; k0 += 32) {
        const u64_t* hr = Hp + (size_t)(w*16 + lm) * HID + k0 + hk;
        frag16 ahi, alo;
#pragma unroll
        for (int j = 0; j < 8; ++j) {
            const uint_t d = (uint_t)(hr[j] >> 32);
            ahi[j] = (short)(d & 0xffffu);
            alo[j] = (short)(d >> 16);
        }
#pragma unroll
        for (int bi = 0; bi < 4; ++bi) {
            const u16x8 bv = cvt8_hi(&Who[(size_t)(n0 + bi*16 + lm) * HID + k0 + hk]);
            acc[bi] = __builtin_amdgcn_mfma_f32_16x16x32_bf16(ahi, (frag16)bv, acc[bi], 0, 0, 0);
            acc[bi] = __builtin_amdgcn_mfma_f32_16x16x32_bf16(alo, (frag16)bv, acc[bi], 0, 0, 0);
        }
    }
#pragma unroll
    for (int bi = 0; bi < 4; ++bi) {
        const int n = n0 + bi*16 + lm;
        const float bias = bho[n];
#pragma unroll
        for (int q = 0; q < 4; ++q) {
            const int b = w*16 + lg*4 + q;
            Out[(size_t)b * OUTF + n] = acc[bi][q] + bias;
        }
    }
}

// ---------------- launcher -----------------------------------------------------
extern "C" void kernel_launch(void* const* d_in, const int* in_sizes, int n_in,
                              void* d_out, int out_size, void* d_ws, size_t ws_size,
                              hipStream_t stream)
{
    const float* X   = (const float*)d_in[0];
    const float* Wih = (const float*)d_in[1];
    const float* bih = (const float*)d_in[2];
    const float* Whh = (const float*)d_in[3];
    const float* bhh = (const float*)d_in[4];
    const float* Who = (const float*)d_in[5];
    const float* bho = (const float*)d_in[6];
    float* Out = (float*)d_out;

    char* ws = (char*)d_ws;
    float* XP = (float*)ws;                                        // 128 MiB
    u64_t* Hbuf = (u64_t*)(ws + (size_t)32768 * 1024 * 4);         // 1 MiB
    // No memset needed: tags are t+1 (1..512); 0xAA-poison and zeros never match.

    xproj_kernel<<<dim3(256, 8), dim3(256), 0, stream>>>(X, Wih, bih, bhh, XP);

    rnn_scan_kernel<<<dim3(GROUPS * BPG), dim3(256), 0, stream>>>(XP, Whh, Hbuf);

    // SEQ=512 -> final step t=511 wrote buffer (511 & 1) = 1
    outproj_kernel<<<dim3(OUTF / 64), dim3(256), 0, stream>>>(Hbuf + (size_t)64 * 1024,
                                                              Who, bho, Out);
}